// Round 3
// baseline (173138.391 us; speedup 1.0000x reference)
//
#include <hip/hip_runtime.h>
#include <math.h>

#define T_STEPS 512
#define BATCH   128
#define HDIM    300
#define M       20

// ---------------- JAX threefry2x32 noise replication ----------------
// jax_threefry_partitionable=True stream (verified passing in round 2).
__device__ __forceinline__ unsigned rotl32(unsigned v, int r) {
    return (v << r) | (v >> (32 - r));
}

__device__ float jax_noise(unsigned i) {
#pragma clang fp contract(off)
    unsigned x0 = 0u;
    unsigned x1 = i;
    const unsigned ks0 = 0u, ks1 = 42u, ks2 = 0u ^ 42u ^ 0x1BD11BDAu;
    x0 += ks0; x1 += ks1;
    x0 += x1; x1 = rotl32(x1, 13); x1 ^= x0;
    x0 += x1; x1 = rotl32(x1, 15); x1 ^= x0;
    x0 += x1; x1 = rotl32(x1, 26); x1 ^= x0;
    x0 += x1; x1 = rotl32(x1, 6);  x1 ^= x0;
    x0 += ks1; x1 += ks2 + 1u;
    x0 += x1; x1 = rotl32(x1, 17); x1 ^= x0;
    x0 += x1; x1 = rotl32(x1, 29); x1 ^= x0;
    x0 += x1; x1 = rotl32(x1, 16); x1 ^= x0;
    x0 += x1; x1 = rotl32(x1, 24); x1 ^= x0;
    x0 += ks2; x1 += ks0 + 2u;
    x0 += x1; x1 = rotl32(x1, 13); x1 ^= x0;
    x0 += x1; x1 = rotl32(x1, 15); x1 ^= x0;
    x0 += x1; x1 = rotl32(x1, 26); x1 ^= x0;
    x0 += x1; x1 = rotl32(x1, 6);  x1 ^= x0;
    x0 += ks0; x1 += ks1 + 3u;
    x0 += x1; x1 = rotl32(x1, 17); x1 ^= x0;
    x0 += x1; x1 = rotl32(x1, 29); x1 ^= x0;
    x0 += x1; x1 = rotl32(x1, 16); x1 ^= x0;
    x0 += x1; x1 = rotl32(x1, 24); x1 ^= x0;
    x0 += ks1; x1 += ks2 + 4u;
    x0 += x1; x1 = rotl32(x1, 13); x1 ^= x0;
    x0 += x1; x1 = rotl32(x1, 15); x1 ^= x0;
    x0 += x1; x1 = rotl32(x1, 26); x1 ^= x0;
    x0 += x1; x1 = rotl32(x1, 6);  x1 ^= x0;
    x0 += ks2; x1 += ks0 + 5u;

    const unsigned bits = x0 ^ x1;
    const unsigned fb = (bits >> 9) | 0x3f800000u;
    float f = __uint_as_float(fb) - 1.0f;
    const float span = 1.0f - 0.01f;
    float v = f * span;
    v = v + 0.01f;
    return fmaxf(0.01f, v);
}

// ---------------- main persistent per-batch kernel ----------------
// grid = 128 blocks (one per batch element), 640 threads = 10 waves.
// GEMMs: each wave takes a K-slice (32/28, 16B-aligned) x ALL columns
// (5 cols/lane => one 320-wide tile per path); partials combined via
// LDS ds_add_f32 atomics. sim and cand run as two sequential phases
// reusing one accumulator buffer (LDS budget < 64KB).
__global__ void __launch_bounds__(640, 3)
wm_kernel(const float* __restrict__ hs,   // (T,B,H)
          const float* __restrict__ msk,  // (T,B)
          const float* __restrict__ We1,  // (300,300)
          const float* __restrict__ be1,  // (300)
          const float* __restrict__ We2,  // (300,1)
          const float* __restrict__ be2,  // (1)
          const float* __restrict__ Ws1,  // (901,300)
          const float* __restrict__ bs1,  // (300)
          const float* __restrict__ Ws2,  // (300,1)
          const float* __restrict__ bs2,  // (1)
          const float* __restrict__ Wu,   // (600,300)
          const float* __restrict__ bu,   // (300)
          float* __restrict__ out)
{
    __shared__ __align__(16) float sh_mem[M][304];   // mem state, padded rows
    __shared__ __align__(16) float accM[M][HDIM];    // shared GEMM accumulator (sim then cand)
    __shared__ __align__(16) float sh_h[304];
    __shared__ float hrowS[HDIM];   // h @ Ws1[300:600]  (qb part of sim)
    __shared__ float hrowC[HDIM];   // h @ Wu[0:300]     (qb part of cand)
    __shared__ float accE[HDIM];    // h @ We1           (ent hidden)
    __shared__ float sh_usage[M], sh_ow[M], sh_indv[M], sh_sim[M];

    const int b    = blockIdx.x;
    const int tid  = threadIdx.x;
    const int wave = tid >> 6;   // 0..9
    const int lane = tid & 63;

    // K-slices: waves 0-4 get 32, waves 5-9 get 28; all starts %4==0 (16B aligned)
    const int klen  = (wave < 5) ? 32 : 28;
    const int kbase = (wave < 5) ? 32 * wave : 160 + 28 * (wave - 5);
    const int nq    = klen >> 2;

    // column assignment: c = lane + 64*cc, cc<5 (clamped for OOB lanes)
    int  cidx[5]; bool cok[5];
#pragma unroll
    for (int cc = 0; cc < 5; ++cc) {
        int c = lane + 64 * cc;
        cok[cc]  = (c < HDIM);
        cidx[cc] = cok[cc] ? c : (HDIM - 1);
    }

    // ---- init state ----
    for (int i = tid; i < M * 304; i += 640) ((float*)sh_mem)[i] = 0.0f;
    for (int i = tid; i < M * HDIM; i += 640) ((float*)accM)[i] = 0.0f;
    if (tid < HDIM) { hrowS[tid] = 0.0f; hrowC[tid] = 0.0f; accE[tid] = 0.0f; }
    if (tid < 304) sh_h[tid] = 0.0f;
    if (tid < M) sh_usage[tid] = 0.0f;
    const float be2v = be2[0];
    const float bs2v = bs2[0];
    __syncthreads();

    for (int t = 0; t < T_STEPS; ++t) {
        const int tb = t * BATCH + b;

        // ---- A: load h ----
        if (tid < HDIM) sh_h[tid] = hs[(size_t)tb * HDIM + tid];
        __syncthreads();

        // ---- B1: sim GEMM (K-sliced, atomically accumulated) ----
        {
            float acc[M][5];
            float hr[5];
#pragma unroll
            for (int cc = 0; cc < 5; ++cc) {
                hr[cc] = 0.0f;
#pragma unroll
                for (int j = 0; j < M; ++j) acc[j][cc] = 0.0f;
            }
            for (int q = 0; q < nq; ++q) {
                const int k = kbase + 4 * q;
                const float4 h4 = *(const float4*)&sh_h[k];
                float wx[5], wy[5], wz[5], ww[5];
#pragma unroll
                for (int cc = 0; cc < 5; ++cc) {
                    const float* pa = Ws1 + (size_t)k * HDIM + cidx[cc];  // rows 0..299  (mem)
                    const float* pb = pa + 90000;                         // rows 300..599 (qb)
                    const float* pc = pa + 180000;                        // rows 600..899 (qb*mem)
                    wx[cc] = fmaf(h4.x, pc[0],        pa[0]);
                    wy[cc] = fmaf(h4.y, pc[HDIM],     pa[HDIM]);
                    wz[cc] = fmaf(h4.z, pc[2 * HDIM], pa[2 * HDIM]);
                    ww[cc] = fmaf(h4.w, pc[3 * HDIM], pa[3 * HDIM]);
                    hr[cc] += h4.x * pb[0] + h4.y * pb[HDIM]
                            + h4.z * pb[2 * HDIM] + h4.w * pb[3 * HDIM];
                }
#pragma unroll
                for (int j = 0; j < M; ++j) {
                    const float4 m4 = *(const float4*)&sh_mem[j][k];
#pragma unroll
                    for (int cc = 0; cc < 5; ++cc)
                        acc[j][cc] += m4.x * wx[cc] + m4.y * wy[cc]
                                    + m4.z * wz[cc] + m4.w * ww[cc];
                }
            }
#pragma unroll
            for (int cc = 0; cc < 5; ++cc) {
                if (cok[cc]) {
#pragma unroll
                    for (int j = 0; j < M; ++j) atomicAdd(&accM[j][cidx[cc]], acc[j][cc]);
                    atomicAdd(&hrowS[cidx[cc]], hr[cc]);
                }
            }
        }
        __syncthreads();

        // ---- C: sim reduction (wave w handles j = w, w+10) ----
#pragma unroll
        for (int jj = 0; jj < 2; ++jj) {
            const int j = wave + 10 * jj;
            const float usg = sh_usage[j];
            float s = 0.0f;
#pragma unroll
            for (int i = 0; i < 5; ++i) {
                const int c = lane + 64 * i;
                if (c < HDIM) {
                    const float pre = accM[j][c] + hrowS[c] + usg * Ws1[270000 + c] + bs1[c];
                    s += fmaxf(pre, 0.0f) * Ws2[c];
                }
            }
            for (int off = 32; off; off >>= 1) s += __shfl_xor(s, off, 64);
            if (lane == 0) sh_sim[j] = s;
        }
        __syncthreads();

        // ---- Z: zero accumulators for B2 (and hrowS for next step's B1) ----
        for (int i = tid; i < M * HDIM; i += 640) ((float*)accM)[i] = 0.0f;
        if (tid < HDIM) { hrowS[tid] = 0.0f; hrowC[tid] = 0.0f; accE[tid] = 0.0f; }
        __syncthreads();

        // ---- B2: cand GEMM + ent GEMV (K-sliced, atomics) ----
        {
            float acc[M][5];
            float hr[5], ee[5];
#pragma unroll
            for (int cc = 0; cc < 5; ++cc) {
                hr[cc] = 0.0f; ee[cc] = 0.0f;
#pragma unroll
                for (int j = 0; j < M; ++j) acc[j][cc] = 0.0f;
            }
            for (int q = 0; q < nq; ++q) {
                const int k = kbase + 4 * q;
                const float4 h4 = *(const float4*)&sh_h[k];
                float wx[5], wy[5], wz[5], ww[5];
#pragma unroll
                for (int cc = 0; cc < 5; ++cc) {
                    const float* pu = Wu  + (size_t)k * HDIM + cidx[cc];  // rows 0..299  (qb)
                    const float* pm = pu + 90000;                         // rows 300..599 (mem)
                    const float* pe = We1 + (size_t)k * HDIM + cidx[cc];
                    wx[cc] = pm[0]; wy[cc] = pm[HDIM];
                    wz[cc] = pm[2 * HDIM]; ww[cc] = pm[3 * HDIM];
                    hr[cc] += h4.x * pu[0] + h4.y * pu[HDIM]
                            + h4.z * pu[2 * HDIM] + h4.w * pu[3 * HDIM];
                    ee[cc] += h4.x * pe[0] + h4.y * pe[HDIM]
                            + h4.z * pe[2 * HDIM] + h4.w * pe[3 * HDIM];
                }
#pragma unroll
                for (int j = 0; j < M; ++j) {
                    const float4 m4 = *(const float4*)&sh_mem[j][k];
#pragma unroll
                    for (int cc = 0; cc < 5; ++cc)
                        acc[j][cc] += m4.x * wx[cc] + m4.y * wy[cc]
                                    + m4.z * wz[cc] + m4.w * ww[cc];
                }
            }
#pragma unroll
            for (int cc = 0; cc < 5; ++cc) {
                if (cok[cc]) {
#pragma unroll
                    for (int j = 0; j < M; ++j) atomicAdd(&accM[j][cidx[cc]], acc[j][cc]);
                    atomicAdd(&hrowC[cidx[cc]], hr[cc]);
                    atomicAdd(&accE[cidx[cc]], ee[cc]);
                }
            }
        }
        __syncthreads();

        // ---- D: decision (wave 0) ----
        if (wave == 0) {
            // ent reduction
            float er = 0.0f;
#pragma unroll
            for (int i = 0; i < 5; ++i) {
                const int c = lane + 64 * i;
                if (c < HDIM) er += fmaxf(accE[c] + be1[c], 0.0f) * We2[c];
            }
            for (int off = 32; off; off >>= 1) er += __shfl_xor(er, off, 64);
            const float es = er + be2v;
            const float entp = (1.0f / (1.0f + expf(-es))) * msk[tb];

            const bool act = lane < M;
            float simj = -INFINITY, usg = 0.0f;
            if (act) { simj = sh_sim[lane] + bs2v; usg = sh_usage[lane]; }

            const float coref = (act && usg > 0.0f) ? 1.0f : 0.0f;
            float comb = act ? ((usg > 0.0f) ? simj : -10000.0f) : -INFINITY;
            float mx = comb;
            for (int off = 32; off; off >>= 1) mx = fmaxf(mx, __shfl_xor(mx, off, 64));
            mx = fmaxf(mx, 0.0f);
            float e = act ? expf(comb - mx) : 0.0f;
            const float eM = expf(0.0f - mx);
            float den = e;
            for (int off = 32; off; off >>= 1) den += __shfl_xor(den, off, 64);
            den += eM;
            const float prob  = e / den;
            const float probM = eM / den;
            float masked = prob * coref;
            float msum = masked;
            for (int off = 32; off; off >>= 1) msum += __shfl_xor(msum, off, 64);
            msum += probM;
            const float dn = msum + 1e-8f;
            const float normj = masked / dn;
            const float normM = probM / dn;
            const float indv = act ? (entp * normj) : 0.0f;
            const float ow_base = entp * normM;

            float nmx = simj;
            for (int off = 32; off; off >>= 1) nmx = fmaxf(nmx, __shfl_xor(nmx, off, 64));
            float ne = act ? expf(simj - nmx) : 0.0f;
            float ns = ne;
            for (int off = 32; off; off >>= 1) ns += __shfl_xor(ns, off, 64);
            const float nsim = ne / ns;

            float ows = act ? (((usg == 0.0f) ? nsim * 100000.0f : 0.0f) + (1.0f - usg))
                            : -INFINITY;
            float mv = ows;
            for (int off = 32; off; off >>= 1) mv = fmaxf(mv, __shfl_xor(mv, off, 64));

            float key = 0.0f;
            if (act && ows == mv) key = jax_noise((unsigned)(tb * M + lane));
            float bv = act ? key : -1.0f;
            int bi = act ? lane : 1023;
            for (int off = 32; off; off >>= 1) {
                float ov = __shfl_xor(bv, off, 64);
                int oi = __shfl_xor(bi, off, 64);
                if (ov > bv || (ov == bv && oi < bi)) { bv = ov; bi = oi; }
            }
            const float ow = (act && lane == bi) ? ow_base : 0.0f;
            const float nu = fminf(1.0f, (ow + indv) + 0.98f * usg);

            if (act) {
                sh_ow[lane] = ow;
                sh_indv[lane] = indv;
                sh_usage[lane] = nu;
                const int base = tb * M + lane;
                out[65536 + base]   = nu;                                   // usage_seq
                out[1376256 + base] = indv * (1.0f - 1e-8f) + 1e-8f;        // coref
                out[2686976 + base] = ow * (1.0f - 1e-8f) + 1e-8f;          // overwrite
            }
            if (lane == 0) out[tb] = entp * (1.0f - 1e-8f) + 1e-8f;          // ent
        }
        __syncthreads();

        // ---- E: memory update (owner zeroes accM for next step's B1) ----
        {
            const int j   = tid >> 5;    // 0..19 (640 = 20*32)
            const int l32 = tid & 31;
            const float owj = sh_ow[j];
            const float inj = sh_indv[j];
            const float keep = 1.0f - owj - inj;
#pragma unroll
            for (int i = 0; i < 10; ++i) {
                const int c = l32 + 32 * i;
                if (c < HDIM) {
                    const float cand = tanhf(accM[j][c] + hrowC[c] + bu[c]);
                    sh_mem[j][c] = owj * sh_h[c] + keep * sh_mem[j][c] + inj * cand;
                    accM[j][c] = 0.0f;
                }
            }
        }
        __syncthreads();
    }
}

extern "C" void kernel_launch(void* const* d_in, const int* in_sizes, int n_in,
                              void* d_out, int out_size, void* d_ws, size_t ws_size,
                              hipStream_t stream) {
    (void)in_sizes; (void)n_in; (void)d_ws; (void)ws_size; (void)out_size;
    const float* hs  = (const float*)d_in[0];
    const float* msk = (const float*)d_in[1];
    const float* We1 = (const float*)d_in[2];
    const float* be1 = (const float*)d_in[3];
    const float* We2 = (const float*)d_in[4];
    const float* be2 = (const float*)d_in[5];
    const float* Ws1 = (const float*)d_in[6];
    const float* bs1 = (const float*)d_in[7];
    const float* Ws2 = (const float*)d_in[8];
    const float* bs2 = (const float*)d_in[9];
    const float* Wu  = (const float*)d_in[10];
    const float* bu  = (const float*)d_in[11];
    float* out = (float*)d_out;

    hipLaunchKernelGGL(wm_kernel, dim3(BATCH), dim3(640), 0, stream,
                       hs, msk, We1, be1, We2, be2, Ws1, bs1, Ws2, bs2, Wu, bu, out);
}

// Round 6
// 77815.674 us; speedup vs baseline: 2.2250x; 2.2250x over previous
//
#include <hip/hip_runtime.h>
#include <math.h>

#define T_STEPS 512
#define BATCH   128
#define HDIM    300
#define M       20

#define SEGSZ   194560          // bytes per weight segment (19 ct * 10240)
#define LOOFF   (6 * 194560)    // offset of lo-part segments

typedef short  bf8   __attribute__((ext_vector_type(8)));   // 8 x bf16 (4 VGPRs)
typedef float  f32x4 __attribute__((ext_vector_type(4)));

// ---------------- JAX threefry2x32 noise (partitionable) — verified passing r2 ----------------
__device__ __forceinline__ unsigned rotl32(unsigned v, int r) { return (v << r) | (v >> (32 - r)); }

__device__ float jax_noise(unsigned i) {
#pragma clang fp contract(off)
    unsigned x0 = 0u, x1 = i;
    const unsigned ks0 = 0u, ks1 = 42u, ks2 = 0u ^ 42u ^ 0x1BD11BDAu;
    x0 += ks0; x1 += ks1;
    x0 += x1; x1 = rotl32(x1,13); x1 ^= x0;  x0 += x1; x1 = rotl32(x1,15); x1 ^= x0;
    x0 += x1; x1 = rotl32(x1,26); x1 ^= x0;  x0 += x1; x1 = rotl32(x1, 6); x1 ^= x0;
    x0 += ks1; x1 += ks2 + 1u;
    x0 += x1; x1 = rotl32(x1,17); x1 ^= x0;  x0 += x1; x1 = rotl32(x1,29); x1 ^= x0;
    x0 += x1; x1 = rotl32(x1,16); x1 ^= x0;  x0 += x1; x1 = rotl32(x1,24); x1 ^= x0;
    x0 += ks2; x1 += ks0 + 2u;
    x0 += x1; x1 = rotl32(x1,13); x1 ^= x0;  x0 += x1; x1 = rotl32(x1,15); x1 ^= x0;
    x0 += x1; x1 = rotl32(x1,26); x1 ^= x0;  x0 += x1; x1 = rotl32(x1, 6); x1 ^= x0;
    x0 += ks0; x1 += ks1 + 3u;
    x0 += x1; x1 = rotl32(x1,17); x1 ^= x0;  x0 += x1; x1 = rotl32(x1,29); x1 ^= x0;
    x0 += x1; x1 = rotl32(x1,16); x1 ^= x0;  x0 += x1; x1 = rotl32(x1,24); x1 ^= x0;
    x0 += ks1; x1 += ks2 + 4u;
    x0 += x1; x1 = rotl32(x1,13); x1 ^= x0;  x0 += x1; x1 = rotl32(x1,15); x1 ^= x0;
    x0 += x1; x1 = rotl32(x1,26); x1 ^= x0;  x0 += x1; x1 = rotl32(x1, 6); x1 ^= x0;
    x0 += ks2; x1 += ks0 + 5u;
    const unsigned bits = x0 ^ x1;
    const unsigned fb = (bits >> 9) | 0x3f800000u;
    float f = __uint_as_float(fb) - 1.0f;
    float v = f * (1.0f - 0.01f);
    v = v + 0.01f;
    return fmaxf(0.01f, v);
}

__device__ __forceinline__ unsigned short f2bf(float v) {
    unsigned u = __float_as_uint(v);
    return (unsigned short)((u + 0x7fffu + ((u >> 16) & 1u)) >> 16);   // RNE
}
__device__ __forceinline__ float bf2f(unsigned short h) {
    return __uint_as_float(((unsigned)h) << 16);
}
__device__ __forceinline__ unsigned short f2bf_lo(float v) {
    return f2bf(v - bf2f(f2bf(v)));     // residual after bf16 rounding (exact subtract)
}

// ---------------- weight prep: f32 -> bf16 hi/lo MFMA A-fragments in d_ws ----------------
// frag elem (lane,i): c = ct*16 + (lane&15), k = kt*32 + (lane>>4)*8 + i
// mats: 0 Ws1a(mem) 1 WuB(mem) 2 Ws1c(h*mem) 3 Ws1b(h) 4 WuA(h) 5 We1(h)
// segs 0..5 = hi parts, segs 6..11 = lo parts.
#define PREP_DWORDS 583680
__global__ void wm_prep(const float* __restrict__ Ws1, const float* __restrict__ Wu,
                        const float* __restrict__ We1, unsigned* __restrict__ wsb) {
    int d = blockIdx.x * 256 + threadIdx.x;
    if (d >= PREP_DWORDS) return;
    int seg = d / 48640;  int r  = d % 48640;
    int part = seg / 6;   int mat = seg % 6;
    int ct  = r / 2560;   int r2 = r % 2560;
    int kt  = r2 / 256;   int r3 = r2 % 256;
    int lane = r3 >> 2;   int dw = r3 & 3;
    int c = ct * 16 + (lane & 15);
    int k0 = kt * 32 + (lane >> 4) * 8 + dw * 2;
    float v0 = 0.0f, v1 = 0.0f;
    if (c < HDIM) {
#pragma unroll
        for (int e = 0; e < 2; ++e) {
            int k = k0 + e;
            float v = 0.0f;
            if (k < HDIM) {
                switch (mat) {
                    case 0: v = Ws1[k * HDIM + c]; break;
                    case 1: v = Wu[(HDIM + k) * HDIM + c]; break;
                    case 2: v = Ws1[(600 + k) * HDIM + c]; break;
                    case 3: v = Ws1[(HDIM + k) * HDIM + c]; break;
                    case 4: v = Wu[k * HDIM + c]; break;
                    default: v = We1[k * HDIM + c]; break;
                }
            }
            if (e == 0) v0 = v; else v1 = v;
        }
    }
    unsigned short h0, h1;
    if (part == 0) { h0 = f2bf(v0);    h1 = f2bf(v1); }
    else           { h0 = f2bf_lo(v0); h1 = f2bf_lo(v1); }
    wsb[d] = (unsigned)h0 | ((unsigned)h1 << 16);
}

__device__ __forceinline__ f32x4 mfma16(bf8 a, bf8 b, f32x4 c) {
    return __builtin_amdgcn_mfma_f32_16x16x32_bf16(a, b, c, 0, 0, 0);
}

// 128 blocks x 1024 threads (16 waves). Waves 0-4: sim chains (Ws1a+Ws1c);
// waves 5-9: cand chains (WuB) + f32 mem ownership; waves 10-15: h-GEMV chains.
// j-tiles: tile0 = rows 0..15, tile1 = rows 4..19 (lanes l15>=12 own j=16..19).
// All GEMM inputs hi/lo bf16-split: A*B ~= Ah*Bh + Ah*Bl + Al*Bh.
__global__ void __launch_bounds__(1024, 4)
wm_main(const float* __restrict__ hs,  const float* __restrict__ msk,
        const float* __restrict__ Ws1, const float* __restrict__ bs1,
        const float* __restrict__ Ws2, const float* __restrict__ bs2,
        const float* __restrict__ bu,  const float* __restrict__ be1,
        const float* __restrict__ We2, const float* __restrict__ be2,
        const char* __restrict__ wsb,  float* __restrict__ out)
{
    __shared__ __align__(16) unsigned short memP [M * 328];  // bf16 hi mem  [j][k]
    __shared__ __align__(16) unsigned short memPl[M * 328];  // bf16 lo mem
    __shared__ __align__(16) unsigned short hmP  [M * 328];  // bf16 hi h*mem
    __shared__ __align__(16) unsigned short hmPl [M * 328];  // bf16 lo h*mem
    __shared__ __align__(16) unsigned short hbf  [320];      // bf16 hi h
    __shared__ __align__(16) unsigned short hbfl [320];      // bf16 lo h
    __shared__ __align__(16) float sh_h[304];
    __shared__ float hrowS[304];    // h @ Ws1b
    __shared__ float hrowC[304];    // h @ WuA
    __shared__ float partS[19][M];  // per-ct sim partials (fixed-order reduce!)
    __shared__ float entAcc[1];
    __shared__ float sh_usg[M], sh_ow[M], sh_ind[M];

    const int b    = blockIdx.x;
    const int tid  = threadIdx.x;
    const int wave = tid >> 6;
    const int lane = tid & 63;
    const int l15  = lane & 15;
    const int q    = lane >> 4;
    const bool roleS = wave < 5;
    const bool roleU = (wave >= 5 && wave < 10);
    const int  base  = roleS ? wave : (roleU ? wave - 5 : 0);
    const int  hw    = wave - 10;

    // ---- init ----
    for (int i = tid; i < M * 328; i += 1024) { memP[i] = 0; memPl[i] = 0; hmP[i] = 0; hmPl[i] = 0; }
    for (int i = tid; i < 320; i += 1024) { hbf[i] = 0; hbfl[i] = 0; }
    if (tid < 304) { sh_h[tid] = 0.0f; hrowS[tid] = 0.0f; hrowC[tid] = 0.0f; }
    if (tid < M) sh_usg[tid] = 0.0f;
    const float bs2v = bs2[0], be2v = be2[0];

    float memreg[4][2][4];   // U-waves: f32 mem master for owned (ct, jt, r)
#pragma unroll
    for (int s = 0; s < 4; ++s)
#pragma unroll
        for (int jt = 0; jt < 2; ++jt)
#pragma unroll
            for (int r = 0; r < 4; ++r) memreg[s][jt][r] = 0.0f;
    __syncthreads();

    for (int t = 0; t < T_STEPS; ++t) {
        const int tb = t * BATCH + b;

        // ---- P0: load h, zero entAcc ----
        if (tid < HDIM) sh_h[tid] = hs[(size_t)tb * HDIM + tid];
        if (tid == 1023) entAcc[0] = 0.0f;
        __syncthreads();

        // ---- P1: U writes hmP hi/lo (h*mem); wave 15 writes hbf hi/lo ----
        if (roleU) {
#pragma unroll
            for (int s = 0; s < 4; ++s) {
                const int ct = base + 5 * s;
                if (ct >= 19) break;
#pragma unroll
                for (int jt = 0; jt < 2; ++jt) {
                    if (jt == 1 && l15 < 12) continue;
                    const int j = jt ? (4 + l15) : l15;
#pragma unroll
                    for (int r = 0; r < 4; ++r) {
                        const int c = ct * 16 + q * 4 + r;
                        if (c < HDIM) {
                            const float hm = memreg[s][jt][r] * sh_h[c];
                            hmP [j * 328 + c] = f2bf(hm);
                            hmPl[j * 328 + c] = f2bf_lo(hm);
                        }
                    }
                }
            }
        } else if (wave == 15) {
            for (int i = lane; i < 150; i += 64) {
                const float v0 = sh_h[2 * i], v1 = sh_h[2 * i + 1];
                ((unsigned*)hbf)[i]  = (unsigned)f2bf(v0)    | ((unsigned)f2bf(v1)    << 16);
                ((unsigned*)hbfl)[i] = (unsigned)f2bf_lo(v0) | ((unsigned)f2bf_lo(v1) << 16);
            }
        }
        __syncthreads();

        // ---- P2: MFMA chains ----
        f32x4 D[4][2];
#pragma unroll
        for (int s = 0; s < 4; ++s) { D[s][0] = (f32x4){0,0,0,0}; D[s][1] = (f32x4){0,0,0,0}; }

        if (roleS) {
            for (int kt = 0; kt < 10; ++kt) {
                const int bo = kt * 32 + q * 8;
                const bf8 bm0h = *(const bf8*)(memP  + l15 * 328 + bo);
                const bf8 bm0l = *(const bf8*)(memPl + l15 * 328 + bo);
                const bf8 bm1h = *(const bf8*)(memP  + (4 + l15) * 328 + bo);
                const bf8 bm1l = *(const bf8*)(memPl + (4 + l15) * 328 + bo);
                const bf8 bh0h = *(const bf8*)(hmP   + l15 * 328 + bo);
                const bf8 bh0l = *(const bf8*)(hmPl  + l15 * 328 + bo);
                const bf8 bh1h = *(const bf8*)(hmP   + (4 + l15) * 328 + bo);
                const bf8 bh1l = *(const bf8*)(hmPl  + (4 + l15) * 328 + bo);
#pragma unroll
                for (int s = 0; s < 4; ++s) {
                    const int ct = base + 5 * s;
                    if (ct >= 19) break;
                    const char* wp = wsb + (size_t)ct * 10240 + kt * 1024 + lane * 16;
                    const bf8 wah = *(const bf8*)(wp);                        // Ws1a hi
                    const bf8 wal = *(const bf8*)(wp + LOOFF);                // Ws1a lo
                    const bf8 wch = *(const bf8*)(wp + 2 * SEGSZ);            // Ws1c hi
                    const bf8 wcl = *(const bf8*)(wp + 2 * SEGSZ + LOOFF);    // Ws1c lo
                    D[s][0] = mfma16(wah, bm0l, D[s][0]);
                    D[s][0] = mfma16(wal, bm0h, D[s][0]);
                    D[s][0] = mfma16(wah, bm0h, D[s][0]);
                    D[s][0] = mfma16(wch, bh0l, D[s][0]);
                    D[s][0] = mfma16(wcl, bh0h, D[s][0]);
                    D[s][0] = mfma16(wch, bh0h, D[s][0]);
                    D[s][1] = mfma16(wah, bm1l, D[s][1]);
                    D[s][1] = mfma16(wal, bm1h, D[s][1]);
                    D[s][1] = mfma16(wah, bm1h, D[s][1]);
                    D[s][1] = mfma16(wch, bh1l, D[s][1]);
                    D[s][1] = mfma16(wcl, bh1h, D[s][1]);
                    D[s][1] = mfma16(wch, bh1h, D[s][1]);
                }
            }
        } else if (roleU) {
            for (int kt = 0; kt < 10; ++kt) {
                const int bo = kt * 32 + q * 8;
                const bf8 bm0h = *(const bf8*)(memP  + l15 * 328 + bo);
                const bf8 bm0l = *(const bf8*)(memPl + l15 * 328 + bo);
                const bf8 bm1h = *(const bf8*)(memP  + (4 + l15) * 328 + bo);
                const bf8 bm1l = *(const bf8*)(memPl + (4 + l15) * 328 + bo);
#pragma unroll
                for (int s = 0; s < 4; ++s) {
                    const int ct = base + 5 * s;
                    if (ct >= 19) break;
                    const char* wp = wsb + SEGSZ + (size_t)ct * 10240 + kt * 1024 + lane * 16;
                    const bf8 wuh = *(const bf8*)(wp);
                    const bf8 wul = *(const bf8*)(wp + LOOFF);
                    D[s][0] = mfma16(wuh, bm0l, D[s][0]);
                    D[s][0] = mfma16(wul, bm0h, D[s][0]);
                    D[s][0] = mfma16(wuh, bm0h, D[s][0]);
                    D[s][1] = mfma16(wuh, bm1l, D[s][1]);
                    D[s][1] = mfma16(wul, bm1h, D[s][1]);
                    D[s][1] = mfma16(wuh, bm1h, D[s][1]);
                }
            }
        } else {
            // h-GEMV waves: kt-outer, 10 live accumulators, 2 LDS reads per kt
            f32x4 Dh[10];
#pragma unroll
            for (int i = 0; i < 10; ++i) Dh[i] = (f32x4){0,0,0,0};
            for (int kt = 0; kt < 10; ++kt) {
                const bf8 bhh = *(const bf8*)((const char*)hbf  + kt * 64 + q * 16);
                const bf8 bhl = *(const bf8*)((const char*)hbfl + kt * 64 + q * 16);
#pragma unroll
                for (int s10 = 0; s10 < 10; ++s10) {
                    const int u = hw + 6 * s10;
                    if (u >= 57) break;
                    const int mat = u / 19, ct = u % 19;
                    const char* wp = wsb + (size_t)(3 + mat) * SEGSZ
                                   + (size_t)ct * 10240 + kt * 1024 + lane * 16;
                    const bf8 ah = *(const bf8*)(wp);
                    const bf8 al = *(const bf8*)(wp + LOOFF);
                    Dh[s10] = mfma16(ah, bhl, Dh[s10]);
                    Dh[s10] = mfma16(al, bhh, Dh[s10]);
                    Dh[s10] = mfma16(ah, bhh, Dh[s10]);
                }
            }
#pragma unroll
            for (int s10 = 0; s10 < 10; ++s10) {
                const int u = hw + 6 * s10;
                if (u >= 57) break;
                const int mat = u / 19, ct = u % 19;
                if (mat == 2) {   // ent partial
                    float er = 0.0f;
#pragma unroll
                    for (int r = 0; r < 4; ++r) {
                        const int c = ct * 16 + q * 4 + r;
                        if (c < HDIM) er += fmaxf(Dh[s10][r] + be1[c], 0.0f) * We2[c];
                    }
                    er += __shfl_xor(er, 16, 64);
                    er += __shfl_xor(er, 32, 64);
                    if (lane == 0) atomicAdd(&entAcc[0], er);
                } else {
                    float* dst = mat ? hrowC : hrowS;
                    if (l15 == 0) {
#pragma unroll
                        for (int r = 0; r < 4; ++r) {
                            const int c = ct * 16 + q * 4 + r;
                            if (c < HDIM) dst[c] = Dh[s10][r];
                        }
                    }
                }
            }
        }
        __syncthreads();

        // ---- P3: sim epilogue (S-waves) -> partS[ct][j] ----
        if (roleS) {
#pragma unroll
            for (int s = 0; s < 4; ++s) {
                const int ct = base + 5 * s;
                if (ct >= 19) break;
                float w3v[4], bs1v[4], ws2v[4], hrS[4];
#pragma unroll
                for (int r = 0; r < 4; ++r) {
                    const int c = ct * 16 + q * 4 + r;
                    const bool ok = c < HDIM;
                    w3v[r]  = ok ? Ws1[900 * HDIM + c] : 0.0f;
                    bs1v[r] = ok ? bs1[c] : 0.0f;
                    ws2v[r] = ok ? Ws2[c] : 0.0f;
                    hrS[r]  = ok ? hrowS[c] : 0.0f;
                }
#pragma unroll
                for (int jt = 0; jt < 2; ++jt) {
                    const int j = jt ? (4 + l15) : l15;
                    const float usg = sh_usg[j];
                    float sv = 0.0f;
#pragma unroll
                    for (int r = 0; r < 4; ++r) {
                        const float pre = D[s][jt][r] + hrS[r] + usg * w3v[r] + bs1v[r];
                        sv += fmaxf(pre, 0.0f) * ws2v[r];
                    }
                    sv += __shfl_xor(sv, 16, 64);
                    sv += __shfl_xor(sv, 32, 64);
                    if (q == 0 && (jt == 0 || l15 >= 12)) partS[ct][j] = sv;
                }
            }
        }
        __syncthreads();

        // ---- P4: decision (wave 0) — identical to round-2-verified logic ----
        if (wave == 0) {
            const bool act = lane < M;
            float simj = -INFINITY, usg = 0.0f;
            if (act) {
                float sacc = 0.0f;
#pragma unroll
                for (int ct = 0; ct < 19; ++ct) sacc += partS[ct][lane];  // fixed order!
                simj = sacc + bs2v;
                usg = sh_usg[lane];
            }
            const float es = entAcc[0] + be2v;
            const float entp = (1.0f / (1.0f + expf(-es))) * msk[tb];

            const float coref = (act && usg > 0.0f) ? 1.0f : 0.0f;
            float comb = act ? ((usg > 0.0f) ? simj : -10000.0f) : -INFINITY;
            float mx = comb;
            for (int off = 32; off; off >>= 1) mx = fmaxf(mx, __shfl_xor(mx, off, 64));
            mx = fmaxf(mx, 0.0f);
            float e = act ? expf(comb - mx) : 0.0f;
            const float eM = expf(0.0f - mx);
            float den = e;
            for (int off = 32; off; off >>= 1) den += __shfl_xor(den, off, 64);
            den += eM;
            const float prob = e / den, probM = eM / den;
            float masked = prob * coref;
            float msum = masked;
            for (int off = 32; off; off >>= 1) msum += __shfl_xor(msum, off, 64);
            msum += probM;
            const float dn = msum + 1e-8f;
            const float indv = act ? (entp * (masked / dn)) : 0.0f;
            const float ow_base = entp * (probM / dn);

            float nmx = simj;
            for (int off = 32; off; off >>= 1) nmx = fmaxf(nmx, __shfl_xor(nmx, off, 64));
            float ne = act ? expf(simj - nmx) : 0.0f;
            float ns = ne;
            for (int off = 32; off; off >>= 1) ns += __shfl_xor(ns, off, 64);
            const float nsim = ne / ns;

            float ows = act ? (((usg == 0.0f) ? nsim * 100000.0f : 0.0f) + (1.0f - usg)) : -INFINITY;
            float mv = ows;
            for (int off = 32; off; off >>= 1) mv = fmaxf(mv, __shfl_xor(mv, off, 64));

            float key = 0.0f;
            if (act && ows == mv) key = jax_noise((unsigned)(tb * M + lane));
            float bv = act ? key : -1.0f;
            int bi = act ? lane : 1023;
            for (int off = 32; off; off >>= 1) {
                float ov = __shfl_xor(bv, off, 64);
                int oi = __shfl_xor(bi, off, 64);
                if (ov > bv || (ov == bv && oi < bi)) { bv = ov; bi = oi; }
            }
            const float ow = (act && lane == bi) ? ow_base : 0.0f;
            const float nu = fminf(1.0f, (ow + indv) + 0.98f * usg);

            if (act) {
                sh_ow[lane] = ow; sh_ind[lane] = indv; sh_usg[lane] = nu;
                const int obase = tb * M + lane;
                out[65536 + obase]   = nu;
                out[1376256 + obase] = indv * (1.0f - 1e-8f) + 1e-8f;
                out[2686976 + obase] = ow * (1.0f - 1e-8f) + 1e-8f;
            }
            if (lane == 0) out[tb] = entp * (1.0f - 1e-8f) + 1e-8f;
        }
        __syncthreads();

        // ---- P5: mem update (U-waves own state); refresh memP hi/lo ----
        if (roleU) {
#pragma unroll
            for (int s = 0; s < 4; ++s) {
                const int ct = base + 5 * s;
                if (ct >= 19) break;
                float buv[4], hrC[4], hv4[4];
#pragma unroll
                for (int r = 0; r < 4; ++r) {
                    const int c = ct * 16 + q * 4 + r;
                    const bool ok = c < HDIM;
                    buv[r] = ok ? bu[c] : 0.0f;
                    hrC[r] = ok ? hrowC[c] : 0.0f;
                    hv4[r] = ok ? sh_h[c] : 0.0f;
                }
#pragma unroll
                for (int jt = 0; jt < 2; ++jt) {
                    if (jt == 1 && l15 < 12) continue;
                    const int j = jt ? (4 + l15) : l15;
                    const float owj = sh_ow[j], inj = sh_ind[j];
                    const float keep = 1.0f - owj - inj;
#pragma unroll
                    for (int r = 0; r < 4; ++r) {
                        const float cand = tanhf(D[s][jt][r] + hrC[r] + buv[r]);
                        const float nm = owj * hv4[r] + keep * memreg[s][jt][r] + inj * cand;
                        memreg[s][jt][r] = nm;
                        const int c = ct * 16 + q * 4 + r;
                        if (c < HDIM) {
                            memP [j * 328 + c] = f2bf(nm);
                            memPl[j * 328 + c] = f2bf_lo(nm);
                        }
                    }
                }
            }
        }
        __syncthreads();
    }
}

extern "C" void kernel_launch(void* const* d_in, const int* in_sizes, int n_in,
                              void* d_out, int out_size, void* d_ws, size_t ws_size,
                              hipStream_t stream) {
    (void)in_sizes; (void)n_in; (void)out_size; (void)ws_size;
    const float* hs  = (const float*)d_in[0];
    const float* msk = (const float*)d_in[1];
    const float* We1 = (const float*)d_in[2];
    const float* be1 = (const float*)d_in[3];
    const float* We2 = (const float*)d_in[4];
    const float* be2 = (const float*)d_in[5];
    const float* Ws1 = (const float*)d_in[6];
    const float* bs1 = (const float*)d_in[7];
    const float* Ws2 = (const float*)d_in[8];
    const float* bs2 = (const float*)d_in[9];
    const float* Wu  = (const float*)d_in[10];
    const float* bu  = (const float*)d_in[11];
    float* out = (float*)d_out;

    hipLaunchKernelGGL(wm_prep, dim3((PREP_DWORDS + 255) / 256), dim3(256), 0, stream,
                       Ws1, Wu, We1, (unsigned*)d_ws);
    hipLaunchKernelGGL(wm_main, dim3(BATCH), dim3(1024), 0, stream,
                       hs, msk, Ws1, bs1, Ws2, bs2, bu, be1, We2, be2,
                       (const char*)d_ws, out);
}